// Round 15
// baseline (2559.787 us; speedup 1.0000x reference)
//
#include <hip/hip_runtime.h>
#include <hip/hip_bf16.h>
#include <math.h>

#define Bn 64
#define Sn 64
#define Tn 20
#define TD 19
#define En 512
#define Hn 1024
#define Vn 32000
#define Kan 100
#define Lnn 50
#define Wnn 8

typedef __attribute__((ext_vector_type(8))) short short8v;
typedef __attribute__((ext_vector_type(4))) float floatx4;
typedef __hip_bfloat16 bf16;
typedef unsigned long long ull;

__device__ __forceinline__ float sigm(float x) { return 1.0f / (1.0f + expf(-x)); }
__device__ __forceinline__ float bfb2f(unsigned int u) {
    return __builtin_bit_cast(float, u << 16);
}
__device__ __forceinline__ unsigned short f2bfb(float f) {
    return __builtin_bit_cast(unsigned short, __float2bfloat16(f));
}

#define ALOAD(p)     __hip_atomic_load((p), __ATOMIC_RELAXED, __HIP_MEMORY_SCOPE_AGENT)
#define ASTORE(p, v) __hip_atomic_store((p), (v), __ATOMIC_RELAXED, __HIP_MEMORY_SCOPE_AGENT)

// 16B staged load via two agent-scope relaxed u64 atomic loads (LLC-cached,
// compiler-tracked dependencies; rounds 8/12/14 verified).
__device__ __forceinline__ uint4 aload16(const ull* base, int ullIdx) {
    ull u0 = ALOAD(base + ullIdx);
    ull u1 = ALOAD(base + ullIdx + 1);
    uint4 v;
    v.x = (unsigned)u0; v.y = (unsigned)(u0 >> 32);
    v.z = (unsigned)u1; v.w = (unsigned)(u1 >> 32);
    return v;
}

// Fully-relaxed inter-block barrier (rounds 8-14 verified).
__device__ __forceinline__ void gbar(unsigned int* c, int tid) {
    __builtin_amdgcn_sched_barrier(0);
    __syncthreads();
    if (tid == 0) {
        __hip_atomic_fetch_add(c, 1u, __ATOMIC_RELAXED, __HIP_MEMORY_SCOPE_AGENT);
        while (__hip_atomic_load(c, __ATOMIC_RELAXED, __HIP_MEMORY_SCOPE_AGENT) < 128u) {
            __builtin_amdgcn_s_sleep(1);
        }
    }
    __syncthreads();
    __builtin_amdgcn_sched_barrier(0);
}

// XOR-swizzled LDS element offset for the mgemm [rows][32] bf16 tiles.
#define EOFF(r, p) (((r) << 5) + ((((p) ^ ((r) & 3))) << 3))

// A-tile LDS offset (64x32 bf16 tile), 2-way max on frag reads.
__device__ __forceinline__ int aswz(int row, int p) {
    return row * 32 + (((p ^ ((row >> 1) & 3))) << 3);
}
// W LDS offset: [32 cols][K] bf16, 16B slot s, 2-way max.
__device__ __forceinline__ int wswz(int col, int s, int K) {
    return col * K + (((s & ~7) | ((s & 7) ^ (col & 7))) << 3);
}

// ===========================================================================
// bf16 MFMA GEMM: C[M,N] = act(A @ W^T + b1 (+ b2)), 128x128 tile, BK=32.
// ===========================================================================
template<int GATHER, int EPI, int ACT>
__global__ __launch_bounds__(256)
void mgemm(const bf16* __restrict__ A, int lda, const int* __restrict__ tok,
           const bf16* __restrict__ W, int ldw,
           const float* __restrict__ b1, const float* __restrict__ b2,
           float* __restrict__ C, int ldc,
           bf16* __restrict__ Cbf, int ldcbf,
           int M, int N, int K)
{
    __shared__ bf16 As[128 * 32];
    __shared__ bf16 Bs[128 * 32];
    const int tid = threadIdx.x;
    const int lane = tid & 63, wv = tid >> 6;
    const int wm = wv >> 1, wn = wv & 1;
    const int n0 = (EPI == 2 ? blockIdx.y : blockIdx.x) * 128;
    const int r0 = (EPI == 2 ? blockIdx.x : blockIdx.y) * 128;
    const int srow = tid >> 2, sp = tid & 3;

    const int ra_r0 = r0 + srow, ra_r1 = r0 + srow + 64;
    const bool av0 = ra_r0 < M, av1 = ra_r1 < M;
    const size_t arow0 = (size_t)(av0 ? (GATHER ? tok[ra_r0] : ra_r0) : 0) * lda;
    const size_t arow1 = (size_t)(av1 ? (GATHER ? tok[ra_r1] : ra_r1) : 0) * lda;
    const size_t wrow0 = (size_t)(n0 + srow) * ldw;
    const size_t wrow1 = (size_t)(n0 + srow + 64) * ldw;

    const uint4 z4 = make_uint4(0, 0, 0, 0);
    uint4 ra0, ra1, rb0, rb1;
#define LOADTILE_G(k0) do { \
        ra0 = av0 ? *((const uint4*)(A + arow0 + (k0)) + sp) : z4; \
        ra1 = av1 ? *((const uint4*)(A + arow1 + (k0)) + sp) : z4; \
        rb0 = *((const uint4*)(W + wrow0 + (k0)) + sp); \
        rb1 = *((const uint4*)(W + wrow1 + (k0)) + sp); \
    } while (0)

    floatx4 acc[4][4] = {};
    const int lr = lane & 15, p2 = lane >> 4;

    LOADTILE_G(0);
    for (int k0 = 0; k0 < K; k0 += 32) {
        __syncthreads();
        *(uint4*)(As + EOFF(srow, sp)) = ra0;
        *(uint4*)(As + EOFF(srow + 64, sp)) = ra1;
        *(uint4*)(Bs + EOFF(srow, sp)) = rb0;
        *(uint4*)(Bs + EOFF(srow + 64, sp)) = rb1;
        __syncthreads();
        if (k0 + 32 < K) LOADTILE_G(k0 + 32);
        short8v aF[4], bF[4];
#pragma unroll
        for (int mf = 0; mf < 4; ++mf)
            aF[mf] = *(const short8v*)(As + EOFF(wm * 64 + mf * 16 + lr, p2));
#pragma unroll
        for (int nf = 0; nf < 4; ++nf)
            bF[nf] = *(const short8v*)(Bs + EOFF(wn * 64 + nf * 16 + lr, p2));
#pragma unroll
        for (int mf = 0; mf < 4; ++mf)
#pragma unroll
            for (int nf = 0; nf < 4; ++nf)
                acc[mf][nf] = __builtin_amdgcn_mfma_f32_16x16x32_bf16(
                    aF[mf], bF[nf], acc[mf][nf], 0, 0, 0);
    }
#undef LOADTILE_G

    const int rbase = r0 + wm * 64 + (lane >> 4) * 4;
    const int nbase = n0 + wn * 64 + (lane & 15);
#pragma unroll
    for (int nf = 0; nf < 4; ++nf) {
        const int n = nbase + nf * 16;
        if (n >= N) continue;
        float bias = b1 ? b1[n] : 0.0f;
        if (b2) bias += b2[n];
#pragma unroll
        for (int mf = 0; mf < 4; ++mf) {
#pragma unroll
            for (int i = 0; i < 4; ++i) {
                const int r = rbase + mf * 16 + i;
                if (r >= M) continue;
                float v = acc[mf][nf][i] + bias;
                if (ACT == 1) v = tanhf(v);
                if (ACT == 2) v = fmaxf(v, 0.0f);
                if (EPI == 2) {
                    int b = r & 63, t = r >> 6;
                    C[(size_t)(b * TD + t) * Vn + n] = v;
                } else {
                    if (C) C[(size_t)r * ldc + n] = v;
                    if (Cbf) Cbf[(size_t)r * ldcbf + n] = __float2bfloat16(v);
                }
            }
        }
    }
}

// ===========================================================================
// Persistent encoder: round-14 version (depth-8 ALOAD ring — verified).
// ===========================================================================
struct EncP {
    const bf16* Wp;      // [4096][1024] gate-permuted
    const bf16* Xg;      // [64][64][4096]
    bf16* hA; bf16* hB;  // [64][1024] double buffer
    const int* len;
    bf16* hlast; bf16* clast;
    unsigned int* cnt;
};

__global__ __launch_bounds__(512, 1)
void enc_persist(EncP p)
{
    __shared__ bf16 Ws_l[32 * 1024];
    __shared__ bf16 Asb[2][64 * 32];
    __shared__ float Gs[64][33];
    const int tid = threadIdx.x;
    const int lane = tid & 63, wv = tid >> 6;
    const int mf = wv >> 1, nf = wv & 1;
    const int blk = blockIdx.x;
    const int n0 = blk * 32;

    for (int idx = tid; idx < 32 * 128; idx += 512) {
        int col = idx >> 7, s = idx & 127;
        uint4 v = *(const uint4*)(p.Wp + (size_t)(n0 + col) * 1024 + s * 8);
        *(uint4*)(Ws_l + wswz(col, s, 1024)) = v;
    }

    const int b = tid >> 3, jl = tid & 7;
    const int j = (n0 >> 2) + jl;
    float c_reg = 0.0f;
    const int hw = b * 256 + blk * 2 + (jl >> 2);
    if ((lane & 3) == 0) ASTORE((ull*)p.hA + hw, 0ull);  // h0 = 0
    const int mylen = p.len[b];

    const int a_rd = aswz(mf * 16 + (lane & 15), lane >> 4);
    const int bcol = nf * 16 + (lane & 15);
    const int bbase = bcol * 1024;
    const int srow = tid >> 2, sp = tid & 3;
    const int a_wr = aswz(srow, sp);
    const int gr = mf * 16 + (lane >> 4) * 4;
    const int gc = nf * 16 + (lane & 15);
    const int sbase = srow * 256 + sp * 2;

    gbar(p.cnt + 0, tid);

    const int NT = 32;
    for (int t = 0; t < Sn; ++t) {
        const ull* hq = (const ull*)((t & 1) ? p.hB : p.hA);
        bf16* hn = (t & 1) ? p.hA : p.hB;
        const bf16* xg = p.Xg + ((size_t)t * Bn + b) * 4096;
        float xf0 = __bfloat162float(xg[j]);
        float xf1 = __bfloat162float(xg[1024 + j]);
        float xf2 = __bfloat162float(xg[2048 + j]);
        float xf3 = __bfloat162float(xg[3072 + j]);
        floatx4 acc = {};
        uint4 ring[8];
        if (tid < 256) {
#pragma unroll
            for (int q = 0; q < 8; ++q) ring[q] = aload16(hq, sbase + q * 8);
            *(uint4*)(Asb[0] + a_wr) = ring[0];
            ring[0] = aload16(hq, sbase + 8 * 8);
        }
        for (int g = 0; g < NT / 8; ++g) {
#pragma unroll
            for (int u = 0; u < 8; ++u) {
                const int i = g * 8 + u;
                __syncthreads();
                if (tid < 256 && i + 1 < NT) {
                    *(uint4*)(Asb[(u + 1) & 1] + a_wr) = ring[(u + 1) & 7];
                    if (i + 9 < NT)
                        ring[(u + 1) & 7] = aload16(hq, sbase + (i + 9) * 8);
                }
                short8v af = *(const short8v*)(Asb[u & 1] + a_rd);
                int s = 4 * i + (lane >> 4);
                short8v bfr = *(const short8v*)(Ws_l + bbase +
                                 (((s & ~7) | ((s & 7) ^ (bcol & 7))) << 3));
                acc = __builtin_amdgcn_mfma_f32_16x16x32_bf16(af, bfr, acc, 0, 0, 0);
            }
        }
        Gs[gr + 0][gc] = acc[0];
        Gs[gr + 1][gc] = acc[1];
        Gs[gr + 2][gc] = acc[2];
        Gs[gr + 3][gc] = acc[3];
        __syncthreads();
        float gi = Gs[b][jl * 4 + 0] + xf0;
        float gf = Gs[b][jl * 4 + 1] + xf1;
        float gg = Gs[b][jl * 4 + 2] + xf2;
        float go = Gs[b][jl * 4 + 3] + xf3;
        float cnv = sigm(gf) * c_reg + sigm(gi) * tanhf(gg);
        float hnv = sigm(go) * tanhf(cnv);
        c_reg = cnv;
        if (t == mylen - 1) {
            p.hlast[b * 1024 + j] = __float2bfloat16(hnv);
            p.clast[b * 1024 + j] = __float2bfloat16(cnv);
        }
        {
            unsigned int q0 = f2bfb(hnv);
            unsigned int q1 = __shfl_down(q0, 1);
            unsigned int q2 = __shfl_down(q0, 2);
            unsigned int q3 = __shfl_down(q0, 3);
            if ((lane & 3) == 0)
                ASTORE((ull*)hn + hw,
                       (ull)q0 | ((ull)q1 << 16) | ((ull)q2 << 32) | ((ull)q3 << 48));
        }
        if (t < Sn - 1) gbar(p.cnt + 1 + t, tid);
    }
}

// ===========================================================================
// Persistent decoder: round-14 (best: 1176us) + depth-8 ALOAD ring in the
// staging loop (enc-verified pattern). Ctx gate at group g==2 (before first
// ctx-tile prefetch, tau=32 at i=23). Attention byte-identical to round 14.
// ===========================================================================
struct DecP {
    const bf16* Wp;      // [4096][2048]
    const bf16* Xg;      // [19][64][4096]
    bf16* hA; bf16* hB;  // [64][1024]
    bf16* ctx;           // [64][1024]
    const float* c0;     // [64][1024]
    const float* akW; const float* akb;
    const float* qkey;   // [64][50][100]
    const bf16* qval;    // [64][50][1024]  (bf16)
    const int* clen;
    bf16* hcat;          // [19][64][2048]
    unsigned int* cnt;   // [64]=init, [65+t]=step-end, [90+t]=ctx-ready
};

__global__ __launch_bounds__(512, 1)
void dec_persist(DecP p)
{
    __shared__ bf16 Ws_l[32 * 2048];
    __shared__ bf16 Asb[2][64 * 32];
    __shared__ float Gs[64][33];
    __shared__ float akey[104];
    __shared__ float ebuf[52];
    __shared__ float wts[52];
    float* hsh = &Gs[0][0];  // 1024 floats, aliases Gs (phase-separated)

    const int tid = threadIdx.x;
    const int lane = tid & 63, wv = tid >> 6;
    const int mf = wv >> 1, nf = wv & 1;
    const int blk = blockIdx.x;
    const int n0 = blk * 32;

    for (int idx = tid; idx < 32 * 256; idx += 512) {
        int col = idx >> 8, s = idx & 255;
        uint4 v = *(const uint4*)(p.Wp + (size_t)(n0 + col) * 2048 + s * 8);
        *(uint4*)(Ws_l + wswz(col, s, 2048)) = v;
    }

    const int b = tid >> 3, jl = tid & 7;
    const int j = (n0 >> 2) + jl;
    float c_reg = p.c0[b * 1024 + j];
    const int hw = b * 256 + blk * 2 + (jl >> 2);

    const int a_rd = aswz(mf * 16 + (lane & 15), lane >> 4);
    const int bcol = nf * 16 + (lane & 15);
    const int bbase = bcol * 2048;
    const int srow = tid >> 2, sp = tid & 3;
    const int a_wr = aswz(srow, sp);
    const int gr = mf * 16 + (lane >> 4) * 4;
    const int gc = nf * 16 + (lane & 15);
    const int sbase = srow * 256 + sp * 2;

    gbar(p.cnt + 64, tid);

    const int NT = 64;
    for (int t = 0; t < TD; ++t) {
        const ull* hq = (const ull*)((t & 1) ? p.hB : p.hA);
        bf16* hn = (t & 1) ? p.hA : p.hB;
        const ull* cq = (const ull*)p.ctx;
        unsigned int* ctxc = p.cnt + 90 + t;

        // ---- attention: block ab computes ctx for batch row ab ----
        if (blk < 64) {
            const int ab = blk;
            if (tid < 256) {
                ull v = ALOAD(hq + ab * 256 + tid);
                hsh[tid * 4 + 0] = bfb2f((unsigned)(v & 0xffff));
                hsh[tid * 4 + 1] = bfb2f((unsigned)((v >> 16) & 0xffff));
                hsh[tid * 4 + 2] = bfb2f((unsigned)((v >> 32) & 0xffff));
                hsh[tid * 4 + 3] = bfb2f((unsigned)(v >> 48));
            }
            __syncthreads();
            for (int k = wv; k < Kan; k += 8) {
                float s = 0.0f;
#pragma unroll
                for (int m = 0; m < 16; ++m)
                    s += hsh[lane + m * 64] * p.akW[(size_t)k * 1024 + lane + m * 64];
                for (int off = 32; off; off >>= 1) s += __shfl_down(s, off);
                if (lane == 0) akey[k] = tanhf(s + p.akb[k]);
            }
            __syncthreads();
            for (int l = wv; l < Lnn; l += 8) {
                const float* qr = p.qkey + (size_t)(ab * Lnn + l) * Kan;
                float s = qr[lane] * akey[lane];
                if (lane < Kan - 64) s += qr[lane + 64] * akey[lane + 64];
                for (int off = 32; off; off >>= 1) s += __shfl_down(s, off);
                if (lane == 0) ebuf[l] = s;
            }
            __syncthreads();
            if (wv == 0) {
                int len = p.clen[ab];
                float e = (lane < Lnn) ? (lane < len ? ebuf[lane] : -1e9f)
                                       : -3.402823466e38f;
                float mx = e;
                for (int off = 32; off; off >>= 1) mx = fmaxf(mx, __shfl_xor(mx, off));
                float pr = (lane < Lnn) ? expf(e - mx) : 0.0f;
                float sm = pr;
                for (int off = 32; off; off >>= 1) sm += __shfl_xor(sm, off);
                if (lane < Lnn) wts[lane] = pr / sm;
            }
            __syncthreads();
#pragma unroll
            for (int pass = 0; pass < 2; ++pass) {
                int jj = tid + pass * 512;
                const bf16* qv = p.qval + (size_t)ab * Lnn * 1024 + jj;
                float s0 = 0.0f, s1 = 0.0f;
                for (int l = 0; l < Lnn; l += 2) {
                    s0 += wts[l] * __bfloat162float(qv[(size_t)l * 1024]);
                    s1 += wts[l + 1] * __bfloat162float(qv[(size_t)(l + 1) * 1024]);
                }
                unsigned short cb = f2bfb(s0 + s1);
                p.hcat[((size_t)t * Bn + ab) * 2048 + 1024 + jj] =
                    __builtin_bit_cast(bf16, cb);
                unsigned int q0 = cb;
                unsigned int q1 = __shfl_down(q0, 1);
                unsigned int q2 = __shfl_down(q0, 2);
                unsigned int q3 = __shfl_down(q0, 3);
                if ((lane & 3) == 0)
                    ASTORE((ull*)p.ctx + ab * 256 + pass * 128 + (tid >> 2),
                           (ull)q0 | ((ull)q1 << 16) | ((ull)q2 << 32) | ((ull)q3 << 48));
            }
            // drain ctx ASTOREs (syncthreads implies per-wave vmcnt 0), announce
            __syncthreads();
            if (tid == 0)
                __hip_atomic_fetch_add(ctxc, 1u, __ATOMIC_RELAXED,
                                       __HIP_MEMORY_SCOPE_AGENT);
        }

        // ---- LSTM over K = 2048 ([h | ctx]); depth-8 ring; gate at g==2 ----
        const bf16* xg = p.Xg + ((size_t)t * Bn + b) * 4096;
        float xf0 = __bfloat162float(xg[j]);
        float xf1 = __bfloat162float(xg[1024 + j]);
        float xf2 = __bfloat162float(xg[2048 + j]);
        float xf3 = __bfloat162float(xg[3072 + j]);
        floatx4 acc = {};
        uint4 ring[8];
        if (tid < 256) {
#pragma unroll
            for (int q = 0; q < 8; ++q) ring[q] = aload16(hq, sbase + q * 8);
            *(uint4*)(Asb[0] + a_wr) = ring[0];
            ring[0] = aload16(hq, sbase + 8 * 8);
        }
        for (int g = 0; g < NT / 8; ++g) {
            if (g == 2) {
                // gate before the first ctx-tile prefetch (tau=32 at i=23);
                // overlaps attention with 16 GEMM iterations.
                __builtin_amdgcn_sched_barrier(0);
                if (tid == 0) {
                    while (__hip_atomic_load(ctxc, __ATOMIC_RELAXED,
                                             __HIP_MEMORY_SCOPE_AGENT) < 64u) {
                        __builtin_amdgcn_s_sleep(1);
                    }
                }
                __syncthreads();
                __builtin_amdgcn_sched_barrier(0);
            }
#pragma unroll
            for (int u = 0; u < 8; ++u) {
                const int i = g * 8 + u;
                __syncthreads();
                if (tid < 256 && i + 1 < NT) {
                    *(uint4*)(Asb[(u + 1) & 1] + a_wr) = ring[(u + 1) & 7];
                    if (i + 9 < NT) {
                        const int tau = i + 9;
                        const ull* aq = (tau < 32) ? hq : cq;
                        ring[(u + 1) & 7] = aload16(aq, sbase + ((tau & 31) << 3));
                    }
                }
                short8v af = *(const short8v*)(Asb[u & 1] + a_rd);
                int s = 4 * i + (lane >> 4);
                short8v bfr = *(const short8v*)(Ws_l + bbase +
                                 (((s & ~7) | ((s & 7) ^ (bcol & 7))) << 3));
                acc = __builtin_amdgcn_mfma_f32_16x16x32_bf16(af, bfr, acc, 0, 0, 0);
            }
        }
        Gs[gr + 0][gc] = acc[0];
        Gs[gr + 1][gc] = acc[1];
        Gs[gr + 2][gc] = acc[2];
        Gs[gr + 3][gc] = acc[3];
        __syncthreads();
        float gi = Gs[b][jl * 4 + 0] + xf0;
        float gf = Gs[b][jl * 4 + 1] + xf1;
        float gg = Gs[b][jl * 4 + 2] + xf2;
        float go = Gs[b][jl * 4 + 3] + xf3;
        float cnv = sigm(gf) * c_reg + sigm(gi) * tanhf(gg);
        float hnv = sigm(go) * tanhf(cnv);
        c_reg = cnv;
        bf16 hb = __float2bfloat16(hnv);
        p.hcat[((size_t)t * Bn + b) * 2048 + j] = hb;
        {
            unsigned int q0 = f2bfb(hnv);
            unsigned int q1 = __shfl_down(q0, 1);
            unsigned int q2 = __shfl_down(q0, 2);
            unsigned int q3 = __shfl_down(q0, 3);
            if ((lane & 3) == 0)
                ASTORE((ull*)hn + hw,
                       (ull)q0 | ((ull)q1 << 16) | ((ull)q2 << 32) | ((ull)q3 << 48));
        }
        if (t < TD - 1) gbar(p.cnt + 65 + t, tid);
    }
}

// ---------------------------------------------------------------------------
__global__ __launch_bounds__(128)
void ctx_embed_kernel(const int* __restrict__ ctc, const float* __restrict__ embed,
                      bf16* __restrict__ ctxe_bf)
{
    const int row = blockIdx.x;  // b*50 + l
    const int tid = threadIdx.x;
    __shared__ int toks[8];
    if (tid < 8) toks[tid] = ctc[row * Wnn + tid];
    __syncthreads();
#pragma unroll
    for (int p = 0; p < 4; ++p) {
        int e = tid + p * 128;
        float s = 0.0f;
#pragma unroll
        for (int w = 0; w < 8; ++w) s += embed[(size_t)toks[w] * En + e];
        ctxe_bf[(size_t)row * En + e] = __float2bfloat16(s * 0.125f);
    }
}

__global__ void prep_tokens(const int* __restrict__ src, const int* __restrict__ trg,
                            int* __restrict__ tokA, int* __restrict__ tokD)
{
    int i = blockIdx.x * 256 + threadIdx.x;
    if (i < Bn * Sn) tokA[i] = src[(i & 63) * Sn + (i >> 6)];
    if (i < TD * Bn) tokD[i] = trg[(i & 63) * Tn + (i >> 6)];
}

__global__ void conv_f2b(const float* __restrict__ src, bf16* __restrict__ dst, int n)
{
    int i = (blockIdx.x * 256 + threadIdx.x) * 4;
    if (i >= n) return;
    float4 v = *(const float4*)(src + i);
    dst[i + 0] = __float2bfloat16(v.x);
    dst[i + 1] = __float2bfloat16(v.y);
    dst[i + 2] = __float2bfloat16(v.z);
    dst[i + 3] = __float2bfloat16(v.w);
}

// pad qk_W [100][512] -> bf16 [128][512]
__global__ void pad_qkw(const float* __restrict__ qkW, bf16* __restrict__ Wp)
{
    int i = blockIdx.x * 256 + threadIdx.x;
    int r = i >> 9;
    Wp[i] = __float2bfloat16(r < Kan ? qkW[(size_t)r * En + (i & 511)] : 0.0f);
}

// gate-permute encoder Whh: Wp[(j*4+g)][k] = Whh[(g*1024+j)][k]
__global__ void perm_enc(const float* __restrict__ Whh, bf16* __restrict__ Wp)
{
    int row = blockIdx.x;
    int j = row >> 2, g = row & 3;
    const float* s = Whh + (size_t)(g * 1024 + j) * 1024;
    bf16* d = Wp + (size_t)row * 1024;
    for (int e = threadIdx.x; e < 1024; e += 256) d[e] = __float2bfloat16(s[e]);
}

// gate-permute decoder [Whh | Wih_ctx]
__global__ void perm_dec(const float* __restrict__ Whh, const float* __restrict__ Wih,
                         bf16* __restrict__ Wp)
{
    int row = blockIdx.x;
    int j = row >> 2, g = row & 3;
    int sr = g * 1024 + j;
    const float* s1 = Whh + (size_t)sr * 1024;
    const float* s2 = Wih + (size_t)sr * 1536 + 512;
    bf16* d = Wp + (size_t)row * 2048;
    for (int e = threadIdx.x; e < 1024; e += 256) {
        d[e] = __float2bfloat16(s1[e]);
        d[1024 + e] = __float2bfloat16(s2[e]);
    }
}

extern "C" void kernel_launch(void* const* d_in, const int* in_sizes, int n_in,
                              void* d_out, int out_size, void* d_ws, size_t ws_size,
                              hipStream_t stream)
{
    (void)in_sizes; (void)n_in; (void)out_size; (void)ws_size;
    const int*   src     = (const int*)d_in[0];
    const int*   srclen  = (const int*)d_in[1];
    const int*   trg     = (const int*)d_in[2];
    const int*   ctc     = (const int*)d_in[3];
    const int*   ctclen  = (const int*)d_in[4];
    const float* embed   = (const float*)d_in[5];
    const float* enc_Wih = (const float*)d_in[6];
    const float* enc_Whh = (const float*)d_in[7];
    const float* enc_bih = (const float*)d_in[8];
    const float* enc_bhh = (const float*)d_in[9];
    const float* dec_Wih = (const float*)d_in[10];
    const float* dec_Whh = (const float*)d_in[11];
    const float* dec_bih = (const float*)d_in[12];
    const float* dec_bhh = (const float*)d_in[13];
    const float* qkW     = (const float*)d_in[14];
    const float* qkb     = (const float*)d_in[15];
    const float* qvW     = (const float*)d_in[16];
    const float* qvb     = (const float*)d_in[17];
    const float* akW     = (const float*)d_in[18];
    const float* akb     = (const float*)d_in[19];
    const float* outW    = (const float*)d_in[20];
    const float* outb    = (const float*)d_in[21];
    const float* wdb     = (const float*)d_in[22];
    const float* hf1W    = (const float*)d_in[23];
    const float* hf1b    = (const float*)d_in[24];
    const float* hf2W    = (const float*)d_in[25];
    const float* hf2b    = (const float*)d_in[26];
    const float* cf1W    = (const float*)d_in[27];
    const float* cf1b    = (const float*)d_in[28];
    const float* cf2W    = (const float*)d_in[29];
    const float* cf2b    = (const float*)d_in[30];
    float* out = (float*)d_out;

    char* ws = (char*)d_ws;
    size_t off = 0;
    auto alloc = [&](size_t bytes) -> void* {
        void* p = ws + off;
        off += (bytes + 255) & ~(size_t)255;
        return p;
    };
    bf16*  embed_bf  = (bf16*)alloc((size_t)Vn * En * 2);
    bf16*  encWih_bf = (bf16*)alloc((size_t)4096 * En * 2);
    bf16*  decWih_bf = (bf16*)alloc((size_t)4096 * 1536 * 2);
    bf16*  qvW_bf    = (bf16*)alloc((size_t)Hn * En * 2);
    bf16*  outW_bf   = (bf16*)alloc((size_t)En * 2048 * 2);
    bf16*  Wenc_p    = (bf16*)alloc((size_t)4096 * 1024 * 2);
    bf16*  Wdec_p    = (bf16*)alloc((size_t)4096 * 2048 * 2);
    bf16*  hf1W_bf   = (bf16*)alloc((size_t)2048 * 1024 * 2);
    bf16*  hf2W_bf   = (bf16*)alloc((size_t)1024 * 2048 * 2);
    bf16*  cf1W_bf   = (bf16*)alloc((size_t)2048 * 1024 * 2);
    bf16*  cf2W_bf   = (bf16*)alloc((size_t)1024 * 2048 * 2);
    bf16*  qkWp      = (bf16*)alloc((size_t)128 * En * 2);
    bf16*  Xenc_bf   = (bf16*)alloc((size_t)Sn * Bn * 4096 * 2);
    bf16*  Xdec_bf   = (bf16*)alloc((size_t)TD * Bn * 4096 * 2);
    float* qkey      = (float*)alloc((size_t)Bn * Lnn * Kan * 4);
    bf16*  qval_bf   = (bf16*)alloc((size_t)Bn * Lnn * Hn * 2);
    bf16*  ctxe_bf   = (bf16*)alloc((size_t)Bn * Lnn * En * 2);
    bf16*  henc0     = (bf16*)alloc((size_t)Bn * Hn * 2);
    bf16*  henc1     = (bf16*)alloc((size_t)Bn * Hn * 2);
    bf16*  hdec0     = (bf16*)alloc((size_t)Bn * Hn * 2);
    bf16*  hdec1     = (bf16*)alloc((size_t)Bn * Hn * 2);
    bf16*  ctxbuf    = (bf16*)alloc((size_t)Bn * Hn * 2);
    float* cbuf0     = (float*)alloc((size_t)Bn * Hn * 4);
    bf16*  hlast_bf  = (bf16*)alloc((size_t)Bn * Hn * 2);
    bf16*  clast_bf  = (bf16*)alloc((size_t)Bn * Hn * 2);
    bf16*  t2h_bf    = (bf16*)alloc((size_t)Bn * 2048 * 2);
    bf16*  t2c_bf    = (bf16*)alloc((size_t)Bn * 2048 * 2);
    int*   tokA      = (int*)alloc((size_t)Bn * Sn * 4);
    int*   tokD      = (int*)alloc((size_t)TD * Bn * 4);
    unsigned int* cnt = (unsigned int*)alloc(128 * 4);
    // hcat_bf / ox_bf alias Xenc_bf (dead after the encoder)
    bf16*  hcat_bf   = Xenc_bf;                              // [1216][2048]
    bf16*  ox_bf     = Xenc_bf + (size_t)TD * Bn * 2048;     // [1216][512]

    hipMemsetAsync(cnt, 0, 128 * 4, stream);

    // ---- weight / embedding conversions ----
    conv_f2b<<<(Vn * En) / 1024, 256, 0, stream>>>(embed, embed_bf, Vn * En);
    conv_f2b<<<(4096 * En) / 1024, 256, 0, stream>>>(enc_Wih, encWih_bf, 4096 * En);
    conv_f2b<<<(4096 * 1536) / 1024, 256, 0, stream>>>(dec_Wih, decWih_bf, 4096 * 1536);
    conv_f2b<<<(Hn * En) / 1024, 256, 0, stream>>>(qvW, qvW_bf, Hn * En);
    conv_f2b<<<(En * 2048) / 1024, 256, 0, stream>>>(outW, outW_bf, En * 2048);
    conv_f2b<<<(2048 * 1024) / 1024, 256, 0, stream>>>(hf1W, hf1W_bf, 2048 * 1024);
    conv_f2b<<<(1024 * 2048) / 1024, 256, 0, stream>>>(hf2W, hf2W_bf, 1024 * 2048);
    conv_f2b<<<(2048 * 1024) / 1024, 256, 0, stream>>>(cf1W, cf1W_bf, 2048 * 1024);
    conv_f2b<<<(1024 * 2048) / 1024, 256, 0, stream>>>(cf2W, cf2W_bf, 1024 * 2048);
    pad_qkw<<<(128 * En) / 256, 256, 0, stream>>>(qkW, qkWp);
    perm_enc<<<4096, 256, 0, stream>>>(enc_Whh, Wenc_p);
    perm_dec<<<4096, 256, 0, stream>>>(dec_Whh, dec_Wih, Wdec_p);
    prep_tokens<<<16, 256, 0, stream>>>(src, trg, tokA, tokD);
    ctx_embed_kernel<<<Bn * Lnn, 128, 0, stream>>>(ctc, embed, ctxe_bf);

    // ---- batched input-gate GEMMs + q projections ----
    mgemm<1, 0, 0><<<dim3(32, 32), 256, 0, stream>>>(
        embed_bf, En, tokA, encWih_bf, En, enc_bih, enc_bhh,
        nullptr, 0, Xenc_bf, 4096, Bn * Sn, 4096, En);
    mgemm<1, 0, 0><<<dim3(32, 10), 256, 0, stream>>>(
        embed_bf, En, tokD, decWih_bf, 1536, dec_bih, dec_bhh,
        nullptr, 0, Xdec_bf, 4096, TD * Bn, 4096, En);
    mgemm<0, 0, 0><<<dim3(8, 25), 256, 0, stream>>>(
        ctxe_bf, En, nullptr, qvW_bf, En, qvb, nullptr,
        nullptr, 0, qval_bf, Hn, Bn * Lnn, Hn, En);
    mgemm<0, 0, 1><<<dim3(1, 25), 256, 0, stream>>>(
        ctxe_bf, En, nullptr, qkWp, En, qkb, nullptr,
        qkey, Kan, nullptr, 0, Bn * Lnn, Kan, En);

    // ---- encoder recurrence: persistent kernel ----
    {
        EncP ep;
        ep.Wp = Wenc_p; ep.Xg = Xenc_bf; ep.hA = henc0; ep.hB = henc1;
        ep.len = srclen; ep.hlast = hlast_bf; ep.clast = clast_bf; ep.cnt = cnt;
        void* args[] = {&ep};
        hipLaunchCooperativeKernel((void*)enc_persist, dim3(128), dim3(512),
                                   args, 0, stream);
    }

    // ---- init_hidden MLPs (MFMA) ----
    mgemm<0, 0, 2><<<dim3(16, 1), 256, 0, stream>>>(
        hlast_bf, Hn, nullptr, hf1W_bf, Hn, hf1b, nullptr,
        nullptr, 0, t2h_bf, 2048, Bn, 2048, Hn);
    mgemm<0, 0, 0><<<dim3(8, 1), 256, 0, stream>>>(
        t2h_bf, 2048, nullptr, hf2W_bf, 2048, hf2b, nullptr,
        nullptr, 0, hdec0, 1024, Bn, Hn, 2048);
    mgemm<0, 0, 2><<<dim3(16, 1), 256, 0, stream>>>(
        clast_bf, Hn, nullptr, cf1W_bf, Hn, cf1b, nullptr,
        nullptr, 0, t2c_bf, 2048, Bn, 2048, Hn);
    mgemm<0, 0, 0><<<dim3(8, 1), 256, 0, stream>>>(
        t2c_bf, 2048, nullptr, cf2W_bf, 2048, cf2b, nullptr,
        cbuf0, Hn, nullptr, 0, Bn, Hn, 2048);

    // ---- decoder recurrence: persistent kernel ----
    {
        DecP dp;
        dp.Wp = Wdec_p; dp.Xg = Xdec_bf; dp.hA = hdec0; dp.hB = hdec1;
        dp.ctx = ctxbuf; dp.c0 = cbuf0;
        dp.akW = akW; dp.akb = akb; dp.qkey = qkey; dp.qval = qval_bf;
        dp.clen = ctclen; dp.hcat = hcat_bf; dp.cnt = cnt;
        void* args[] = {&dp};
        hipLaunchCooperativeKernel((void*)dec_persist, dim3(128), dim3(512),
                                   args, 0, stream);
    }

    // ---- batched epilogue: ox then logits (grid transposed for L2 reuse) ----
    mgemm<0, 0, 0><<<dim3(4, 10), 256, 0, stream>>>(
        hcat_bf, 2048, nullptr, outW_bf, 2048, outb, nullptr,
        nullptr, 0, ox_bf, En, TD * Bn, En, 2048);
    mgemm<0, 2, 0><<<dim3(10, Vn / 128), 256, 0, stream>>>(
        ox_bf, En, nullptr, embed_bf, En, wdb, nullptr,
        out, 0, nullptr, 0, TD * Bn, Vn, En);
}

// Round 16
// 2319.789 us; speedup vs baseline: 1.1035x; 1.1035x over previous
//
#include <hip/hip_runtime.h>
#include <hip/hip_bf16.h>
#include <math.h>

#define Bn 64
#define Sn 64
#define Tn 20
#define TD 19
#define En 512
#define Hn 1024
#define Vn 32000
#define Kan 100
#define Lnn 50
#define Wnn 8

typedef __attribute__((ext_vector_type(8))) short short8v;
typedef __attribute__((ext_vector_type(4))) float floatx4;
typedef __hip_bfloat16 bf16;
typedef unsigned long long ull;

__device__ __forceinline__ float sigm(float x) { return 1.0f / (1.0f + expf(-x)); }
__device__ __forceinline__ float bfb2f(unsigned int u) {
    return __builtin_bit_cast(float, u << 16);
}
__device__ __forceinline__ unsigned short f2bfb(float f) {
    return __builtin_bit_cast(unsigned short, __float2bfloat16(f));
}

#define ALOAD(p)     __hip_atomic_load((p), __ATOMIC_RELAXED, __HIP_MEMORY_SCOPE_AGENT)
#define ASTORE(p, v) __hip_atomic_store((p), (v), __ATOMIC_RELAXED, __HIP_MEMORY_SCOPE_AGENT)

// 16B staged load via two agent-scope relaxed u64 atomic loads (LLC-cached,
// compiler-tracked dependencies; rounds 8/12/14 verified).
__device__ __forceinline__ uint4 aload16(const ull* base, int ullIdx) {
    ull u0 = ALOAD(base + ullIdx);
    ull u1 = ALOAD(base + ullIdx + 1);
    uint4 v;
    v.x = (unsigned)u0; v.y = (unsigned)(u0 >> 32);
    v.z = (unsigned)u1; v.w = (unsigned)(u1 >> 32);
    return v;
}

// Fully-relaxed inter-block barrier (rounds 8-14 verified).
__device__ __forceinline__ void gbar(unsigned int* c, int tid) {
    __builtin_amdgcn_sched_barrier(0);
    __syncthreads();
    if (tid == 0) {
        __hip_atomic_fetch_add(c, 1u, __ATOMIC_RELAXED, __HIP_MEMORY_SCOPE_AGENT);
        while (__hip_atomic_load(c, __ATOMIC_RELAXED, __HIP_MEMORY_SCOPE_AGENT) < 128u) {
            __builtin_amdgcn_s_sleep(1);
        }
    }
    __syncthreads();
    __builtin_amdgcn_sched_barrier(0);
}

// XOR-swizzled LDS element offset for the mgemm [rows][32] bf16 tiles.
#define EOFF(r, p) (((r) << 5) + ((((p) ^ ((r) & 3))) << 3))

// A-tile LDS offset (64x32 bf16 tile), 2-way max on frag reads.
__device__ __forceinline__ int aswz(int row, int p) {
    return row * 32 + (((p ^ ((row >> 1) & 3))) << 3);
}
// W LDS offset: [32 cols][K] bf16, 16B slot s, 2-way max.
__device__ __forceinline__ int wswz(int col, int s, int K) {
    return col * K + (((s & ~7) | ((s & 7) ^ (col & 7))) << 3);
}

// ===========================================================================
// bf16 MFMA GEMM: C[M,N] = act(A @ W^T + b1 (+ b2)), 128x128 tile, BK=32.
// ===========================================================================
template<int GATHER, int EPI, int ACT>
__global__ __launch_bounds__(256)
void mgemm(const bf16* __restrict__ A, int lda, const int* __restrict__ tok,
           const bf16* __restrict__ W, int ldw,
           const float* __restrict__ b1, const float* __restrict__ b2,
           float* __restrict__ C, int ldc,
           bf16* __restrict__ Cbf, int ldcbf,
           int M, int N, int K)
{
    __shared__ bf16 As[128 * 32];
    __shared__ bf16 Bs[128 * 32];
    const int tid = threadIdx.x;
    const int lane = tid & 63, wv = tid >> 6;
    const int wm = wv >> 1, wn = wv & 1;
    const int n0 = (EPI == 2 ? blockIdx.y : blockIdx.x) * 128;
    const int r0 = (EPI == 2 ? blockIdx.x : blockIdx.y) * 128;
    const int srow = tid >> 2, sp = tid & 3;

    const int ra_r0 = r0 + srow, ra_r1 = r0 + srow + 64;
    const bool av0 = ra_r0 < M, av1 = ra_r1 < M;
    const size_t arow0 = (size_t)(av0 ? (GATHER ? tok[ra_r0] : ra_r0) : 0) * lda;
    const size_t arow1 = (size_t)(av1 ? (GATHER ? tok[ra_r1] : ra_r1) : 0) * lda;
    const size_t wrow0 = (size_t)(n0 + srow) * ldw;
    const size_t wrow1 = (size_t)(n0 + srow + 64) * ldw;

    const uint4 z4 = make_uint4(0, 0, 0, 0);
    uint4 ra0, ra1, rb0, rb1;
#define LOADTILE_G(k0) do { \
        ra0 = av0 ? *((const uint4*)(A + arow0 + (k0)) + sp) : z4; \
        ra1 = av1 ? *((const uint4*)(A + arow1 + (k0)) + sp) : z4; \
        rb0 = *((const uint4*)(W + wrow0 + (k0)) + sp); \
        rb1 = *((const uint4*)(W + wrow1 + (k0)) + sp); \
    } while (0)

    floatx4 acc[4][4] = {};
    const int lr = lane & 15, p2 = lane >> 4;

    LOADTILE_G(0);
    for (int k0 = 0; k0 < K; k0 += 32) {
        __syncthreads();
        *(uint4*)(As + EOFF(srow, sp)) = ra0;
        *(uint4*)(As + EOFF(srow + 64, sp)) = ra1;
        *(uint4*)(Bs + EOFF(srow, sp)) = rb0;
        *(uint4*)(Bs + EOFF(srow + 64, sp)) = rb1;
        __syncthreads();
        if (k0 + 32 < K) LOADTILE_G(k0 + 32);
        short8v aF[4], bF[4];
#pragma unroll
        for (int mf = 0; mf < 4; ++mf)
            aF[mf] = *(const short8v*)(As + EOFF(wm * 64 + mf * 16 + lr, p2));
#pragma unroll
        for (int nf = 0; nf < 4; ++nf)
            bF[nf] = *(const short8v*)(Bs + EOFF(wn * 64 + nf * 16 + lr, p2));
#pragma unroll
        for (int mf = 0; mf < 4; ++mf)
#pragma unroll
            for (int nf = 0; nf < 4; ++nf)
                acc[mf][nf] = __builtin_amdgcn_mfma_f32_16x16x32_bf16(
                    aF[mf], bF[nf], acc[mf][nf], 0, 0, 0);
    }
#undef LOADTILE_G

    const int rbase = r0 + wm * 64 + (lane >> 4) * 4;
    const int nbase = n0 + wn * 64 + (lane & 15);
#pragma unroll
    for (int nf = 0; nf < 4; ++nf) {
        const int n = nbase + nf * 16;
        if (n >= N) continue;
        float bias = b1 ? b1[n] : 0.0f;
        if (b2) bias += b2[n];
#pragma unroll
        for (int mf = 0; mf < 4; ++mf) {
#pragma unroll
            for (int i = 0; i < 4; ++i) {
                const int r = rbase + mf * 16 + i;
                if (r >= M) continue;
                float v = acc[mf][nf][i] + bias;
                if (ACT == 1) v = tanhf(v);
                if (ACT == 2) v = fmaxf(v, 0.0f);
                if (EPI == 2) {
                    int b = r & 63, t = r >> 6;
                    C[(size_t)(b * TD + t) * Vn + n] = v;
                } else {
                    if (C) C[(size_t)r * ldc + n] = v;
                    if (Cbf) Cbf[(size_t)r * ldcbf + n] = __float2bfloat16(v);
                }
            }
        }
    }
}

// ===========================================================================
// Persistent encoder: depth-8 ALOAD ring (verified best for enc).
// ===========================================================================
struct EncP {
    const bf16* Wp;      // [4096][1024] gate-permuted
    const bf16* Xg;      // [64][64][4096]
    bf16* hA; bf16* hB;  // [64][1024] double buffer
    const int* len;
    bf16* hlast; bf16* clast;
    unsigned int* cnt;
};

__global__ __launch_bounds__(512, 1)
void enc_persist(EncP p)
{
    __shared__ bf16 Ws_l[32 * 1024];
    __shared__ bf16 Asb[2][64 * 32];
    __shared__ float Gs[64][33];
    const int tid = threadIdx.x;
    const int lane = tid & 63, wv = tid >> 6;
    const int mf = wv >> 1, nf = wv & 1;
    const int blk = blockIdx.x;
    const int n0 = blk * 32;

    for (int idx = tid; idx < 32 * 128; idx += 512) {
        int col = idx >> 7, s = idx & 127;
        uint4 v = *(const uint4*)(p.Wp + (size_t)(n0 + col) * 1024 + s * 8);
        *(uint4*)(Ws_l + wswz(col, s, 1024)) = v;
    }

    const int b = tid >> 3, jl = tid & 7;
    const int j = (n0 >> 2) + jl;
    float c_reg = 0.0f;
    const int hw = b * 256 + blk * 2 + (jl >> 2);
    if ((lane & 3) == 0) ASTORE((ull*)p.hA + hw, 0ull);  // h0 = 0
    const int mylen = p.len[b];

    const int a_rd = aswz(mf * 16 + (lane & 15), lane >> 4);
    const int bcol = nf * 16 + (lane & 15);
    const int bbase = bcol * 1024;
    const int srow = tid >> 2, sp = tid & 3;
    const int a_wr = aswz(srow, sp);
    const int gr = mf * 16 + (lane >> 4) * 4;
    const int gc = nf * 16 + (lane & 15);
    const int sbase = srow * 256 + sp * 2;

    gbar(p.cnt + 0, tid);

    const int NT = 32;
    for (int t = 0; t < Sn; ++t) {
        const ull* hq = (const ull*)((t & 1) ? p.hB : p.hA);
        bf16* hn = (t & 1) ? p.hA : p.hB;
        const bf16* xg = p.Xg + ((size_t)t * Bn + b) * 4096;
        float xf0 = __bfloat162float(xg[j]);
        float xf1 = __bfloat162float(xg[1024 + j]);
        float xf2 = __bfloat162float(xg[2048 + j]);
        float xf3 = __bfloat162float(xg[3072 + j]);
        floatx4 acc = {};
        uint4 ring[8];
        if (tid < 256) {
#pragma unroll
            for (int q = 0; q < 8; ++q) ring[q] = aload16(hq, sbase + q * 8);
            *(uint4*)(Asb[0] + a_wr) = ring[0];
            ring[0] = aload16(hq, sbase + 8 * 8);
        }
        for (int g = 0; g < NT / 8; ++g) {
#pragma unroll
            for (int u = 0; u < 8; ++u) {
                const int i = g * 8 + u;
                __syncthreads();
                if (tid < 256 && i + 1 < NT) {
                    *(uint4*)(Asb[(u + 1) & 1] + a_wr) = ring[(u + 1) & 7];
                    if (i + 9 < NT)
                        ring[(u + 1) & 7] = aload16(hq, sbase + (i + 9) * 8);
                }
                short8v af = *(const short8v*)(Asb[u & 1] + a_rd);
                int s = 4 * i + (lane >> 4);
                short8v bfr = *(const short8v*)(Ws_l + bbase +
                                 (((s & ~7) | ((s & 7) ^ (bcol & 7))) << 3));
                acc = __builtin_amdgcn_mfma_f32_16x16x32_bf16(af, bfr, acc, 0, 0, 0);
            }
        }
        Gs[gr + 0][gc] = acc[0];
        Gs[gr + 1][gc] = acc[1];
        Gs[gr + 2][gc] = acc[2];
        Gs[gr + 3][gc] = acc[3];
        __syncthreads();
        float gi = Gs[b][jl * 4 + 0] + xf0;
        float gf = Gs[b][jl * 4 + 1] + xf1;
        float gg = Gs[b][jl * 4 + 2] + xf2;
        float go = Gs[b][jl * 4 + 3] + xf3;
        float cnv = sigm(gf) * c_reg + sigm(gi) * tanhf(gg);
        float hnv = sigm(go) * tanhf(cnv);
        c_reg = cnv;
        if (t == mylen - 1) {
            p.hlast[b * 1024 + j] = __float2bfloat16(hnv);
            p.clast[b * 1024 + j] = __float2bfloat16(cnv);
        }
        {
            unsigned int q0 = f2bfb(hnv);
            unsigned int q1 = __shfl_down(q0, 1);
            unsigned int q2 = __shfl_down(q0, 2);
            unsigned int q3 = __shfl_down(q0, 3);
            if ((lane & 3) == 0)
                ASTORE((ull*)hn + hw,
                       (ull)q0 | ((ull)q1 << 16) | ((ull)q2 << 32) | ((ull)q3 << 48));
        }
        if (t < Sn - 1) gbar(p.cnt + 1 + t, tid);
    }
}

// ===========================================================================
// Persistent decoder: round-14 verified best (1176us): 1-deep ALOAD staging,
// single gbar/step, ctx gate at i==30, bf16 qval.
// ===========================================================================
struct DecP {
    const bf16* Wp;      // [4096][2048]
    const bf16* Xg;      // [19][64][4096]
    bf16* hA; bf16* hB;  // [64][1024]
    bf16* ctx;           // [64][1024]
    const float* c0;     // [64][1024]
    const float* akW; const float* akb;
    const float* qkey;   // [64][50][100]
    const bf16* qval;    // [64][50][1024]  (bf16)
    const int* clen;
    bf16* hcat;          // [19][64][2048]
    unsigned int* cnt;   // [64]=init, [65+t]=step-end, [90+t]=ctx-ready
};

__global__ __launch_bounds__(512, 1)
void dec_persist(DecP p)
{
    __shared__ bf16 Ws_l[32 * 2048];
    __shared__ bf16 Asb[2][64 * 32];
    __shared__ float Gs[64][33];
    __shared__ float akey[104];
    __shared__ float ebuf[52];
    __shared__ float wts[52];
    float* hsh = &Gs[0][0];  // 1024 floats, aliases Gs (phase-separated)

    const int tid = threadIdx.x;
    const int lane = tid & 63, wv = tid >> 6;
    const int mf = wv >> 1, nf = wv & 1;
    const int blk = blockIdx.x;
    const int n0 = blk * 32;

    for (int idx = tid; idx < 32 * 256; idx += 512) {
        int col = idx >> 8, s = idx & 255;
        uint4 v = *(const uint4*)(p.Wp + (size_t)(n0 + col) * 2048 + s * 8);
        *(uint4*)(Ws_l + wswz(col, s, 2048)) = v;
    }

    const int b = tid >> 3, jl = tid & 7;
    const int j = (n0 >> 2) + jl;
    float c_reg = p.c0[b * 1024 + j];
    const int hw = b * 256 + blk * 2 + (jl >> 2);

    const int a_rd = aswz(mf * 16 + (lane & 15), lane >> 4);
    const int bcol = nf * 16 + (lane & 15);
    const int bbase = bcol * 2048;
    const int srow = tid >> 2, sp = tid & 3;
    const int a_wr = aswz(srow, sp);
    const int gr = mf * 16 + (lane >> 4) * 4;
    const int gc = nf * 16 + (lane & 15);
    const int sbase = srow * 256 + sp * 2;

    gbar(p.cnt + 64, tid);

    for (int t = 0; t < TD; ++t) {
        const ull* hq = (const ull*)((t & 1) ? p.hB : p.hA);
        bf16* hn = (t & 1) ? p.hA : p.hB;
        const ull* cq = (const ull*)p.ctx;
        unsigned int* ctxc = p.cnt + 90 + t;

        // ---- attention: block ab computes ctx for batch row ab ----
        if (blk < 64) {
            const int ab = blk;
            if (tid < 256) {
                ull v = ALOAD(hq + ab * 256 + tid);
                hsh[tid * 4 + 0] = bfb2f((unsigned)(v & 0xffff));
                hsh[tid * 4 + 1] = bfb2f((unsigned)((v >> 16) & 0xffff));
                hsh[tid * 4 + 2] = bfb2f((unsigned)((v >> 32) & 0xffff));
                hsh[tid * 4 + 3] = bfb2f((unsigned)(v >> 48));
            }
            __syncthreads();
            for (int k = wv; k < Kan; k += 8) {
                float s = 0.0f;
#pragma unroll
                for (int m = 0; m < 16; ++m)
                    s += hsh[lane + m * 64] * p.akW[(size_t)k * 1024 + lane + m * 64];
                for (int off = 32; off; off >>= 1) s += __shfl_down(s, off);
                if (lane == 0) akey[k] = tanhf(s + p.akb[k]);
            }
            __syncthreads();
            for (int l = wv; l < Lnn; l += 8) {
                const float* qr = p.qkey + (size_t)(ab * Lnn + l) * Kan;
                float s = qr[lane] * akey[lane];
                if (lane < Kan - 64) s += qr[lane + 64] * akey[lane + 64];
                for (int off = 32; off; off >>= 1) s += __shfl_down(s, off);
                if (lane == 0) ebuf[l] = s;
            }
            __syncthreads();
            if (wv == 0) {
                int len = p.clen[ab];
                float e = (lane < Lnn) ? (lane < len ? ebuf[lane] : -1e9f)
                                       : -3.402823466e38f;
                float mx = e;
                for (int off = 32; off; off >>= 1) mx = fmaxf(mx, __shfl_xor(mx, off));
                float pr = (lane < Lnn) ? expf(e - mx) : 0.0f;
                float sm = pr;
                for (int off = 32; off; off >>= 1) sm += __shfl_xor(sm, off);
                if (lane < Lnn) wts[lane] = pr / sm;
            }
            __syncthreads();
#pragma unroll
            for (int pass = 0; pass < 2; ++pass) {
                int jj = tid + pass * 512;
                const bf16* qv = p.qval + (size_t)ab * Lnn * 1024 + jj;
                float s0 = 0.0f, s1 = 0.0f;
                for (int l = 0; l < Lnn; l += 2) {
                    s0 += wts[l] * __bfloat162float(qv[(size_t)l * 1024]);
                    s1 += wts[l + 1] * __bfloat162float(qv[(size_t)(l + 1) * 1024]);
                }
                unsigned short cb = f2bfb(s0 + s1);
                p.hcat[((size_t)t * Bn + ab) * 2048 + 1024 + jj] =
                    __builtin_bit_cast(bf16, cb);
                unsigned int q0 = cb;
                unsigned int q1 = __shfl_down(q0, 1);
                unsigned int q2 = __shfl_down(q0, 2);
                unsigned int q3 = __shfl_down(q0, 3);
                if ((lane & 3) == 0)
                    ASTORE((ull*)p.ctx + ab * 256 + pass * 128 + (tid >> 2),
                           (ull)q0 | ((ull)q1 << 16) | ((ull)q2 << 32) | ((ull)q3 << 48));
            }
            // drain ctx ASTOREs (syncthreads implies per-wave vmcnt 0), announce
            __syncthreads();
            if (tid == 0)
                __hip_atomic_fetch_add(ctxc, 1u, __ATOMIC_RELAXED,
                                       __HIP_MEMORY_SCOPE_AGENT);
        }

        // ---- LSTM over K = 2048 ([h | ctx]); ctx gate at tile 32 ----
        const bf16* xg = p.Xg + ((size_t)t * Bn + b) * 4096;
        float xf0 = __bfloat162float(xg[j]);
        float xf1 = __bfloat162float(xg[1024 + j]);
        float xf2 = __bfloat162float(xg[2048 + j]);
        float xf3 = __bfloat162float(xg[3072 + j]);
        floatx4 acc = {};
        uint4 ra;
        if (tid < 256) ra = aload16(hq, sbase);
        __syncthreads();
        if (tid < 256) *(uint4*)(Asb[0] + a_wr) = ra;
        if (tid < 256) ra = aload16(hq, sbase + 8);
        for (int i = 0; i < 64; ++i) {
            if (i == 30) {
                __builtin_amdgcn_sched_barrier(0);
                if (tid == 0) {
                    while (__hip_atomic_load(ctxc, __ATOMIC_RELAXED,
                                             __HIP_MEMORY_SCOPE_AGENT) < 64u) {
                        __builtin_amdgcn_s_sleep(1);
                    }
                }
                __syncthreads();
                __builtin_amdgcn_sched_barrier(0);
            }
            __syncthreads();
            if (i + 1 < 64 && tid < 256) {
                *(uint4*)(Asb[(i + 1) & 1] + a_wr) = ra;
                if (i + 2 < 64) {
                    const ull* aq = (i + 2 < 32) ? hq : cq;
                    ra = aload16(aq, sbase + (((i + 2) & 31) << 3));
                }
            }
            short8v af = *(const short8v*)(Asb[i & 1] + a_rd);
            int s = 4 * i + (lane >> 4);
            short8v bfr = *(const short8v*)(Ws_l + bbase +
                             (((s & ~7) | ((s & 7) ^ (bcol & 7))) << 3));
            acc = __builtin_amdgcn_mfma_f32_16x16x32_bf16(af, bfr, acc, 0, 0, 0);
        }
        Gs[gr + 0][gc] = acc[0];
        Gs[gr + 1][gc] = acc[1];
        Gs[gr + 2][gc] = acc[2];
        Gs[gr + 3][gc] = acc[3];
        __syncthreads();
        float gi = Gs[b][jl * 4 + 0] + xf0;
        float gf = Gs[b][jl * 4 + 1] + xf1;
        float gg = Gs[b][jl * 4 + 2] + xf2;
        float go = Gs[b][jl * 4 + 3] + xf3;
        float cnv = sigm(gf) * c_reg + sigm(gi) * tanhf(gg);
        float hnv = sigm(go) * tanhf(cnv);
        c_reg = cnv;
        bf16 hb = __float2bfloat16(hnv);
        p.hcat[((size_t)t * Bn + b) * 2048 + j] = hb;
        {
            unsigned int q0 = f2bfb(hnv);
            unsigned int q1 = __shfl_down(q0, 1);
            unsigned int q2 = __shfl_down(q0, 2);
            unsigned int q3 = __shfl_down(q0, 3);
            if ((lane & 3) == 0)
                ASTORE((ull*)hn + hw,
                       (ull)q0 | ((ull)q1 << 16) | ((ull)q2 << 32) | ((ull)q3 << 48));
        }
        if (t < TD - 1) gbar(p.cnt + 65 + t, tid);
    }
}

// ---------------------------------------------------------------------------
__global__ __launch_bounds__(128)
void ctx_embed_kernel(const int* __restrict__ ctc, const float* __restrict__ embed,
                      bf16* __restrict__ ctxe_bf)
{
    const int row = blockIdx.x;  // b*50 + l
    const int tid = threadIdx.x;
    __shared__ int toks[8];
    if (tid < 8) toks[tid] = ctc[row * Wnn + tid];
    __syncthreads();
#pragma unroll
    for (int p = 0; p < 4; ++p) {
        int e = tid + p * 128;
        float s = 0.0f;
#pragma unroll
        for (int w = 0; w < 8; ++w) s += embed[(size_t)toks[w] * En + e];
        ctxe_bf[(size_t)row * En + e] = __float2bfloat16(s * 0.125f);
    }
}

__global__ void prep_tokens(const int* __restrict__ src, const int* __restrict__ trg,
                            int* __restrict__ tokA, int* __restrict__ tokD)
{
    int i = blockIdx.x * 256 + threadIdx.x;
    if (i < Bn * Sn) tokA[i] = src[(i & 63) * Sn + (i >> 6)];
    if (i < TD * Bn) tokD[i] = trg[(i & 63) * Tn + (i >> 6)];
}

__global__ void conv_f2b(const float* __restrict__ src, bf16* __restrict__ dst, int n)
{
    int i = (blockIdx.x * 256 + threadIdx.x) * 4;
    if (i >= n) return;
    float4 v = *(const float4*)(src + i);
    dst[i + 0] = __float2bfloat16(v.x);
    dst[i + 1] = __float2bfloat16(v.y);
    dst[i + 2] = __float2bfloat16(v.z);
    dst[i + 3] = __float2bfloat16(v.w);
}

// pad qk_W [100][512] -> bf16 [128][512]
__global__ void pad_qkw(const float* __restrict__ qkW, bf16* __restrict__ Wp)
{
    int i = blockIdx.x * 256 + threadIdx.x;
    int r = i >> 9;
    Wp[i] = __float2bfloat16(r < Kan ? qkW[(size_t)r * En + (i & 511)] : 0.0f);
}

// gate-permute encoder Whh: Wp[(j*4+g)][k] = Whh[(g*1024+j)][k]
__global__ void perm_enc(const float* __restrict__ Whh, bf16* __restrict__ Wp)
{
    int row = blockIdx.x;
    int j = row >> 2, g = row & 3;
    const float* s = Whh + (size_t)(g * 1024 + j) * 1024;
    bf16* d = Wp + (size_t)row * 1024;
    for (int e = threadIdx.x; e < 1024; e += 256) d[e] = __float2bfloat16(s[e]);
}

// gate-permute decoder [Whh | Wih_ctx]
__global__ void perm_dec(const float* __restrict__ Whh, const float* __restrict__ Wih,
                         bf16* __restrict__ Wp)
{
    int row = blockIdx.x;
    int j = row >> 2, g = row & 3;
    int sr = g * 1024 + j;
    const float* s1 = Whh + (size_t)sr * 1024;
    const float* s2 = Wih + (size_t)sr * 1536 + 512;
    bf16* d = Wp + (size_t)row * 2048;
    for (int e = threadIdx.x; e < 1024; e += 256) {
        d[e] = __float2bfloat16(s1[e]);
        d[1024 + e] = __float2bfloat16(s2[e]);
    }
}

extern "C" void kernel_launch(void* const* d_in, const int* in_sizes, int n_in,
                              void* d_out, int out_size, void* d_ws, size_t ws_size,
                              hipStream_t stream)
{
    (void)in_sizes; (void)n_in; (void)out_size; (void)ws_size;
    const int*   src     = (const int*)d_in[0];
    const int*   srclen  = (const int*)d_in[1];
    const int*   trg     = (const int*)d_in[2];
    const int*   ctc     = (const int*)d_in[3];
    const int*   ctclen  = (const int*)d_in[4];
    const float* embed   = (const float*)d_in[5];
    const float* enc_Wih = (const float*)d_in[6];
    const float* enc_Whh = (const float*)d_in[7];
    const float* enc_bih = (const float*)d_in[8];
    const float* enc_bhh = (const float*)d_in[9];
    const float* dec_Wih = (const float*)d_in[10];
    const float* dec_Whh = (const float*)d_in[11];
    const float* dec_bih = (const float*)d_in[12];
    const float* dec_bhh = (const float*)d_in[13];
    const float* qkW     = (const float*)d_in[14];
    const float* qkb     = (const float*)d_in[15];
    const float* qvW     = (const float*)d_in[16];
    const float* qvb     = (const float*)d_in[17];
    const float* akW     = (const float*)d_in[18];
    const float* akb     = (const float*)d_in[19];
    const float* outW    = (const float*)d_in[20];
    const float* outb    = (const float*)d_in[21];
    const float* wdb     = (const float*)d_in[22];
    const float* hf1W    = (const float*)d_in[23];
    const float* hf1b    = (const float*)d_in[24];
    const float* hf2W    = (const float*)d_in[25];
    const float* hf2b    = (const float*)d_in[26];
    const float* cf1W    = (const float*)d_in[27];
    const float* cf1b    = (const float*)d_in[28];
    const float* cf2W    = (const float*)d_in[29];
    const float* cf2b    = (const float*)d_in[30];
    float* out = (float*)d_out;

    char* ws = (char*)d_ws;
    size_t off = 0;
    auto alloc = [&](size_t bytes) -> void* {
        void* p = ws + off;
        off += (bytes + 255) & ~(size_t)255;
        return p;
    };
    bf16*  embed_bf  = (bf16*)alloc((size_t)Vn * En * 2);
    bf16*  encWih_bf = (bf16*)alloc((size_t)4096 * En * 2);
    bf16*  decWih_bf = (bf16*)alloc((size_t)4096 * 1536 * 2);
    bf16*  qvW_bf    = (bf16*)alloc((size_t)Hn * En * 2);
    bf16*  outW_bf   = (bf16*)alloc((size_t)En * 2048 * 2);
    bf16*  Wenc_p    = (bf16*)alloc((size_t)4096 * 1024 * 2);
    bf16*  Wdec_p    = (bf16*)alloc((size_t)4096 * 2048 * 2);
    bf16*  hf1W_bf   = (bf16*)alloc((size_t)2048 * 1024 * 2);
    bf16*  hf2W_bf   = (bf16*)alloc((size_t)1024 * 2048 * 2);
    bf16*  cf1W_bf   = (bf16*)alloc((size_t)2048 * 1024 * 2);
    bf16*  cf2W_bf   = (bf16*)alloc((size_t)1024 * 2048 * 2);
    bf16*  qkWp      = (bf16*)alloc((size_t)128 * En * 2);
    bf16*  Xenc_bf   = (bf16*)alloc((size_t)Sn * Bn * 4096 * 2);
    bf16*  Xdec_bf   = (bf16*)alloc((size_t)TD * Bn * 4096 * 2);
    float* qkey      = (float*)alloc((size_t)Bn * Lnn * Kan * 4);
    bf16*  qval_bf   = (bf16*)alloc((size_t)Bn * Lnn * Hn * 2);
    bf16*  ctxe_bf   = (bf16*)alloc((size_t)Bn * Lnn * En * 2);
    bf16*  henc0     = (bf16*)alloc((size_t)Bn * Hn * 2);
    bf16*  henc1     = (bf16*)alloc((size_t)Bn * Hn * 2);
    bf16*  hdec0     = (bf16*)alloc((size_t)Bn * Hn * 2);
    bf16*  hdec1     = (bf16*)alloc((size_t)Bn * Hn * 2);
    bf16*  ctxbuf    = (bf16*)alloc((size_t)Bn * Hn * 2);
    float* cbuf0     = (float*)alloc((size_t)Bn * Hn * 4);
    bf16*  hlast_bf  = (bf16*)alloc((size_t)Bn * Hn * 2);
    bf16*  clast_bf  = (bf16*)alloc((size_t)Bn * Hn * 2);
    bf16*  t2h_bf    = (bf16*)alloc((size_t)Bn * 2048 * 2);
    bf16*  t2c_bf    = (bf16*)alloc((size_t)Bn * 2048 * 2);
    int*   tokA      = (int*)alloc((size_t)Bn * Sn * 4);
    int*   tokD      = (int*)alloc((size_t)TD * Bn * 4);
    unsigned int* cnt = (unsigned int*)alloc(128 * 4);
    // hcat_bf / ox_bf alias Xenc_bf (dead after the encoder)
    bf16*  hcat_bf   = Xenc_bf;                              // [1216][2048]
    bf16*  ox_bf     = Xenc_bf + (size_t)TD * Bn * 2048;     // [1216][512]

    hipMemsetAsync(cnt, 0, 128 * 4, stream);

    // ---- weight / embedding conversions ----
    conv_f2b<<<(Vn * En) / 1024, 256, 0, stream>>>(embed, embed_bf, Vn * En);
    conv_f2b<<<(4096 * En) / 1024, 256, 0, stream>>>(enc_Wih, encWih_bf, 4096 * En);
    conv_f2b<<<(4096 * 1536) / 1024, 256, 0, stream>>>(dec_Wih, decWih_bf, 4096 * 1536);
    conv_f2b<<<(Hn * En) / 1024, 256, 0, stream>>>(qvW, qvW_bf, Hn * En);
    conv_f2b<<<(En * 2048) / 1024, 256, 0, stream>>>(outW, outW_bf, En * 2048);
    conv_f2b<<<(2048 * 1024) / 1024, 256, 0, stream>>>(hf1W, hf1W_bf, 2048 * 1024);
    conv_f2b<<<(1024 * 2048) / 1024, 256, 0, stream>>>(hf2W, hf2W_bf, 1024 * 2048);
    conv_f2b<<<(2048 * 1024) / 1024, 256, 0, stream>>>(cf1W, cf1W_bf, 2048 * 1024);
    conv_f2b<<<(1024 * 2048) / 1024, 256, 0, stream>>>(cf2W, cf2W_bf, 1024 * 2048);
    pad_qkw<<<(128 * En) / 256, 256, 0, stream>>>(qkW, qkWp);
    perm_enc<<<4096, 256, 0, stream>>>(enc_Whh, Wenc_p);
    perm_dec<<<4096, 256, 0, stream>>>(dec_Whh, dec_Wih, Wdec_p);
    prep_tokens<<<16, 256, 0, stream>>>(src, trg, tokA, tokD);
    ctx_embed_kernel<<<Bn * Lnn, 128, 0, stream>>>(ctc, embed, ctxe_bf);

    // ---- batched input-gate GEMMs + q projections ----
    mgemm<1, 0, 0><<<dim3(32, 32), 256, 0, stream>>>(
        embed_bf, En, tokA, encWih_bf, En, enc_bih, enc_bhh,
        nullptr, 0, Xenc_bf, 4096, Bn * Sn, 4096, En);
    mgemm<1, 0, 0><<<dim3(32, 10), 256, 0, stream>>>(
        embed_bf, En, tokD, decWih_bf, 1536, dec_bih, dec_bhh,
        nullptr, 0, Xdec_bf, 4096, TD * Bn, 4096, En);
    mgemm<0, 0, 0><<<dim3(8, 25), 256, 0, stream>>>(
        ctxe_bf, En, nullptr, qvW_bf, En, qvb, nullptr,
        nullptr, 0, qval_bf, Hn, Bn * Lnn, Hn, En);
    mgemm<0, 0, 1><<<dim3(1, 25), 256, 0, stream>>>(
        ctxe_bf, En, nullptr, qkWp, En, qkb, nullptr,
        qkey, Kan, nullptr, 0, Bn * Lnn, Kan, En);

    // ---- encoder recurrence: persistent kernel ----
    {
        EncP ep;
        ep.Wp = Wenc_p; ep.Xg = Xenc_bf; ep.hA = henc0; ep.hB = henc1;
        ep.len = srclen; ep.hlast = hlast_bf; ep.clast = clast_bf; ep.cnt = cnt;
        void* args[] = {&ep};
        hipLaunchCooperativeKernel((void*)enc_persist, dim3(128), dim3(512),
                                   args, 0, stream);
    }

    // ---- init_hidden MLPs (MFMA) ----
    mgemm<0, 0, 2><<<dim3(16, 1), 256, 0, stream>>>(
        hlast_bf, Hn, nullptr, hf1W_bf, Hn, hf1b, nullptr,
        nullptr, 0, t2h_bf, 2048, Bn, 2048, Hn);
    mgemm<0, 0, 0><<<dim3(8, 1), 256, 0, stream>>>(
        t2h_bf, 2048, nullptr, hf2W_bf, 2048, hf2b, nullptr,
        nullptr, 0, hdec0, 1024, Bn, Hn, 2048);
    mgemm<0, 0, 2><<<dim3(16, 1), 256, 0, stream>>>(
        clast_bf, Hn, nullptr, cf1W_bf, Hn, cf1b, nullptr,
        nullptr, 0, t2c_bf, 2048, Bn, 2048, Hn);
    mgemm<0, 0, 0><<<dim3(8, 1), 256, 0, stream>>>(
        t2c_bf, 2048, nullptr, cf2W_bf, 2048, cf2b, nullptr,
        cbuf0, Hn, nullptr, 0, Bn, Hn, 2048);

    // ---- decoder recurrence: persistent kernel ----
    {
        DecP dp;
        dp.Wp = Wdec_p; dp.Xg = Xdec_bf; dp.hA = hdec0; dp.hB = hdec1;
        dp.ctx = ctxbuf; dp.c0 = cbuf0;
        dp.akW = akW; dp.akb = akb; dp.qkey = qkey; dp.qval = qval_bf;
        dp.clen = ctclen; dp.hcat = hcat_bf; dp.cnt = cnt;
        void* args[] = {&dp};
        hipLaunchCooperativeKernel((void*)dec_persist, dim3(128), dim3(512),
                                   args, 0, stream);
    }

    // ---- batched epilogue: ox then logits (grid transposed for L2 reuse) ----
    mgemm<0, 0, 0><<<dim3(4, 10), 256, 0, stream>>>(
        hcat_bf, 2048, nullptr, outW_bf, 2048, outb, nullptr,
        nullptr, 0, ox_bf, En, TD * Bn, En, 2048);
    mgemm<0, 2, 0><<<dim3(10, Vn / 128), 256, 0, stream>>>(
        ox_bf, En, nullptr, embed_bf, En, wdb, nullptr,
        out, 0, nullptr, 0, TD * Bn, Vn, En);
}